// Round 4
// baseline (200.122 us; speedup 1.0000x reference)
//
#include <hip/hip_runtime.h>
#include <hip/hip_bf16.h>
#include <stdint.h>

typedef __bf16 bf16x8 __attribute__((ext_vector_type(8)));
typedef float f32x4 __attribute__((ext_vector_type(4)));

#define EPS 1e-8f

// ---------------------------------------------------------------------------
// Pre-kernel: prototype norms (64 rows x 512 fp32) -> pn[64] fp32 in d_ws.
// One wave per prototype row.
// ---------------------------------------------------------------------------
__global__ __launch_bounds__(64) void proto_norms_kernel(
    const float* __restrict__ proto, float* __restrict__ pn) {
  const int c = blockIdx.x;
  const int lane = threadIdx.x;
  const float4 t0 = *(const float4*)(proto + (size_t)c * 512 + lane * 8);
  const float4 t1 = *(const float4*)(proto + (size_t)c * 512 + lane * 8 + 4);
  float s = t0.x * t0.x + t0.y * t0.y + t0.z * t0.z + t0.w * t0.w +
            t1.x * t1.x + t1.y * t1.y + t1.z * t1.z + t1.w * t1.w;
#pragma unroll
  for (int off = 32; off > 0; off >>= 1) s += __shfl_xor(s, off);
  if (lane == 0) pn[c] = sqrtf(s);
}

// ---------------------------------------------------------------------------
// Main kernel: 512 threads = 8 waves, 128 x-rows/block, all 64 prototypes.
// Protos converted fp32->bf16 into LDS (XOR-swizzled 16B chunks, 64 KiB).
// x loaded fp32 straight into registers in MFMA A-fragment layout, converted
// to bf16 in-flight; fp32 row norms from the same loads.
// C/D binding: the m89/m91-verified mapping — D row (x-row) = quad*4+reg,
// D col (proto idx) = lane&15. Output is fp32 (reference output dtype).
// No __syncthreads inside the K loop (LDS is read-only there).
// ---------------------------------------------------------------------------
__global__ __launch_bounds__(512, 4) void protonet_main_kernel(
    const float* __restrict__ x,
    const float* __restrict__ proto,
    const float* __restrict__ pn,
    float* __restrict__ out) {
  __shared__ char lds[64 * 1024];  // protos (bf16) during K loop, out-staging after

  const int tid = threadIdx.x;

  // ---- stage prototypes global(fp32) -> LDS(bf16), XOR swizzle by row ----
  // chunk i (of 4096, 8 elems each): row = i>>6, cc = i&63, stored at
  // row*1024 + (cc ^ (row&15))*16
#pragma unroll
  for (int j = 0; j < 8; ++j) {
    int i = tid + j * 512;
    int row = i >> 6;
    int cc = i & 63;
    int sc = cc ^ (row & 15);
    const f32x4 p0 = *(const f32x4*)(proto + (size_t)i * 8);
    const f32x4 p1 = *(const f32x4*)(proto + (size_t)i * 8 + 4);
    bf16x8 b;
#pragma unroll
    for (int e = 0; e < 4; ++e) {
      b[e] = (__bf16)p0[e];
      b[e + 4] = (__bf16)p1[e];
    }
    *(bf16x8*)(lds + row * 1024 + sc * 16) = b;
  }
  __syncthreads();

  const int wave = tid >> 6;
  const int lane = tid & 63;
  const int m = lane & 15;     // x-row within 16-row tile (A-dim) / proto col (B-dim)
  const int quad = lane >> 4;  // k-subchunk selector

  const long rowbase = (long)blockIdx.x * 128 + wave * 16;
  const float* xptr = x + (size_t)(rowbase + m) * 512 + quad * 8;

  f32x4 acc0 = {0.f, 0.f, 0.f, 0.f};
  f32x4 acc1 = {0.f, 0.f, 0.f, 0.f};
  f32x4 acc2 = {0.f, 0.f, 0.f, 0.f};
  f32x4 acc3 = {0.f, 0.f, 0.f, 0.f};
  float xnsq = 0.f;

#pragma unroll 4
  for (int kc = 0; kc < 16; ++kc) {
    // A fragment source: x[rowbase+m][kc*32 + quad*8 + 0..7], fp32
    const f32x4 v0 = *(const f32x4*)(xptr + kc * 32);
    const f32x4 v1 = *(const f32x4*)(xptr + kc * 32 + 4);
    bf16x8 a;
#pragma unroll
    for (int e = 0; e < 4; ++e) {
      xnsq += v0[e] * v0[e];
      xnsq += v1[e] * v1[e];
      a[e] = (__bf16)v0[e];
      a[e + 4] = (__bf16)v1[e];
    }
    // B fragments: proto[16t+m][kc*32 + quad*8 + 0..7], swizzled chunk addr
    const int ccq = kc * 4 + quad;
    bf16x8 b0 = *(const bf16x8*)(lds + (0 * 16 + m) * 1024 + (ccq ^ m) * 16);
    bf16x8 b1 = *(const bf16x8*)(lds + (1 * 16 + m) * 1024 + (ccq ^ m) * 16);
    bf16x8 b2 = *(const bf16x8*)(lds + (2 * 16 + m) * 1024 + (ccq ^ m) * 16);
    bf16x8 b3 = *(const bf16x8*)(lds + (3 * 16 + m) * 1024 + (ccq ^ m) * 16);
    acc0 = __builtin_amdgcn_mfma_f32_16x16x32_bf16(a, b0, acc0, 0, 0, 0);
    acc1 = __builtin_amdgcn_mfma_f32_16x16x32_bf16(a, b1, acc1, 0, 0, 0);
    acc2 = __builtin_amdgcn_mfma_f32_16x16x32_bf16(a, b2, acc2, 0, 0, 0);
    acc3 = __builtin_amdgcn_mfma_f32_16x16x32_bf16(a, b3, acc3, 0, 0, 0);
  }

  // ---- row norm of row m: sum partials across lanes {m,m+16,m+32,m+48} ----
  xnsq += __shfl_xor(xnsq, 16);
  xnsq += __shfl_xor(xnsq, 32);
  const float xn = sqrtf(xnsq);  // lane holds xn of x-row (lane&15)

  // xn for the 4 D-rows this lane owns: D row = quad*4 + r
  float xnr[4];
#pragma unroll
  for (int r = 0; r < 4; ++r) xnr[r] = __shfl(xn, quad * 4 + r);

  // pn for the 4 proto tiles this lane owns: proto idx = 16t + m
  float pnv[4];
#pragma unroll
  for (int t = 0; t < 4; ++t) pnv[t] = pn[16 * t + m];

  // ---- all waves done reading protos; reuse LDS as fp32 [128][64] ----
  __syncthreads();
  float* outs = (float*)lds;
  const f32x4 accs[4] = {acc0, acc1, acc2, acc3};
#pragma unroll
  for (int t = 0; t < 4; ++t) {
#pragma unroll
    for (int r = 0; r < 4; ++r) {
      float denom = fmaxf(xnr[r] * pnv[t], EPS);
      // D[quad*4+r][16t+m] = dot(x[rowbase+quad*4+r], proto[16t+m])
      outs[(wave * 16 + quad * 4 + r) * 64 + 16 * t + m] = -accs[t][r] / denom;
    }
  }
  __syncthreads();

  // ---- coalesced copy-out: block's output span is contiguous 32 KiB ----
  uint4* dst = (uint4*)(out + (size_t)blockIdx.x * 128 * 64);
  const uint4* src = (const uint4*)lds;
#pragma unroll
  for (int k = 0; k < 4; ++k) dst[tid + 512 * k] = src[tid + 512 * k];
}

// ---------------------------------------------------------------------------
extern "C" void kernel_launch(void* const* d_in, const int* in_sizes, int n_in,
                              void* d_out, int out_size, void* d_ws, size_t ws_size,
                              hipStream_t stream) {
  const float* x = (const float*)d_in[0];      // fp32 [B,512]
  const float* proto = (const float*)d_in[1];  // fp32 [64,512]
  float* out = (float*)d_out;                  // fp32 [B,64]
  float* pn = (float*)d_ws;                    // [64] fp32 scratch

  const int B = in_sizes[0] / 512;  // 65536

  proto_norms_kernel<<<dim3(64), dim3(64), 0, stream>>>(proto, pn);
  protonet_main_kernel<<<dim3(B / 128), dim3(512), 0, stream>>>(x, proto, pn, out);
}